// Round 2
// baseline (629.296 us; speedup 1.0000x reference)
//
#include <hip/hip_runtime.h>
#include <hip/hip_bf16.h>

#define N_NODES 50000
#define F_IN    602
#define H_DIM   32
#define C_OUT   41
#define E_EDGES 800000
#define BN_EPS  1e-5f

#define GEMM_GRID 1024   // blocks; each handles row-groups blockIdx.x and +1024

// ---------------------------------------------------------------------------
// K1 v2: p = x @ W1a  (N x 602 x 32). Barrier-free streaming GEMM.
// W^T staged in LDS as float4 k-quads, two phases of <=76 quads (38.9 KB).
// Wave = 8 rows (half-wave: 4 rows x 32 cols). x loads are 32-lane broadcasts.
// Accumulators persist in registers across phases; no barriers in k-loop.
// ---------------------------------------------------------------------------
__global__ __launch_bounds__(256) void k_gemm_in_v2(
    const float* __restrict__ x, const float* __restrict__ W,
    float* __restrict__ p) {
  __shared__ float4 wq[76 * 32];
  const int tid = threadIdx.x;
  const int w = tid >> 6;        // wave 0..3
  const int l = tid & 63;
  const int h = l >> 5;          // half-wave
  const int c = l & 31;          // output column

  const int g0 = blockIdx.x;
  const int g1 = blockIdx.x + GEMM_GRID;
  const bool has1 = (g1 * 32 < N_NODES);
  int rb[2] = { g0 * 32 + w * 8 + h * 4, g1 * 32 + w * 8 + h * 4 };

  float acc[2][4] = {};

  for (int ph = 0; ph < 2; ph++) {
    const int qbase = ph ? 76 : 0;
    const int nq    = ph ? 75 : 76;
    if (ph) __syncthreads();           // protect LDS restage
    for (int i = tid; i < nq * 32; i += 256) {
      int q = i >> 5, cc = i & 31;
      int k4 = (qbase + q) * 4;
      float4 v;
      v.x = W[(size_t)k4 * H_DIM + cc];
      v.y = (k4 + 1 < F_IN) ? W[(size_t)(k4 + 1) * H_DIM + cc] : 0.f;
      v.z = (k4 + 2 < F_IN) ? W[(size_t)(k4 + 2) * H_DIM + cc] : 0.f;
      v.w = (k4 + 3 < F_IN) ? W[(size_t)(k4 + 3) * H_DIM + cc] : 0.f;
      wq[q * 32 + cc] = v;
    }
    __syncthreads();

    for (int gi = 0; gi < 2; gi++) {
      if (gi && !has1) break;
      const int r0 = rb[gi];
      const float* xr[4];
      #pragma unroll
      for (int i = 0; i < 4; i++) {
        int rr = r0 + i; if (rr > N_NODES - 1) rr = N_NODES - 1;  // clamp loads
        xr[i] = x + (size_t)rr * F_IN;
      }
      #pragma unroll 2
      for (int q = 0; q < nq; q++) {
        float4 w4 = wq[q * 32 + c];          // lanes 0..31: stride 16B, no conflict
        const int k = (qbase + q) * 4;
        const bool tail = (qbase + q) == 150;  // k=600..603: only 2 valid
        #pragma unroll
        for (int i = 0; i < 4; i++) {
          float2 a = *(const float2*)(xr[i] + k);
          float2 bv;
          if (tail) { bv.x = 0.f; bv.y = 0.f; }
          else      { bv = *(const float2*)(xr[i] + k + 2); }
          acc[gi][i] += a.x * w4.x + a.y * w4.y + bv.x * w4.z + bv.y * w4.w;
        }
      }
    }
  }

  #pragma unroll
  for (int gi = 0; gi < 2; gi++) {
    if (gi && !has1) break;
    const int r0 = rb[gi];
    #pragma unroll
    for (int i = 0; i < 4; i++) {
      int rr = r0 + i;
      if (rr < N_NODES) p[(size_t)rr * H_DIM + c] = acc[gi][i];
    }
  }
}

// ---------------------------------------------------------------------------
// CSR build: histogram -> 3-kernel exclusive scan -> fill
// ---------------------------------------------------------------------------
__global__ __launch_bounds__(256) void k_hist(const int* __restrict__ row,
                                              int* __restrict__ deg) {
  int e = blockIdx.x * 256 + threadIdx.x;
  if (e < E_EDGES) atomicAdd(&deg[row[e]], 1);
}

__global__ __launch_bounds__(256) void k_scanA(const int* __restrict__ deg,
                                               int* __restrict__ start,
                                               int* __restrict__ bsum) {
  __shared__ int sc[256];
  int t = threadIdx.x, i = blockIdx.x * 256 + t;
  int v = (i < N_NODES) ? deg[i] : 0;
  sc[t] = v;
  __syncthreads();
  #pragma unroll
  for (int off = 1; off < 256; off <<= 1) {
    int u = (t >= off) ? sc[t - off] : 0;
    __syncthreads();
    sc[t] += u;
    __syncthreads();
  }
  if (i < N_NODES) start[i] = sc[t] - v;   // exclusive, block-local
  if (t == 255) bsum[blockIdx.x] = sc[255];
}

__global__ __launch_bounds__(256) void k_scanB(const int* __restrict__ bsum,
                                               int* __restrict__ boff, int nb) {
  __shared__ int sc[256];
  int t = threadIdx.x;
  int v = (t < nb) ? bsum[t] : 0;
  sc[t] = v;
  __syncthreads();
  #pragma unroll
  for (int off = 1; off < 256; off <<= 1) {
    int u = (t >= off) ? sc[t - off] : 0;
    __syncthreads();
    sc[t] += u;
    __syncthreads();
  }
  if (t < nb) boff[t] = sc[t] - v;   // exclusive
}

__global__ __launch_bounds__(256) void k_scanC(int* __restrict__ start,
                                               const int* __restrict__ boff,
                                               int* __restrict__ cursor) {
  int i = blockIdx.x * 256 + threadIdx.x;
  if (i < N_NODES) {
    int s = start[i] + boff[blockIdx.x];
    start[i] = s;
    cursor[i] = s;
  }
  if (i == 0) start[N_NODES] = E_EDGES;
}

__global__ __launch_bounds__(256) void k_fill(const int* __restrict__ row,
                                              const int* __restrict__ col,
                                              int* __restrict__ cursor,
                                              int* __restrict__ ecol) {
  int e = blockIdx.x * 256 + threadIdx.x;
  if (e < E_EDGES) {
    int pos = atomicAdd(&cursor[row[e]], 1);
    ecol[pos] = col[e];
  }
}

// ---------------------------------------------------------------------------
// Gather-aggregate: z[n][c] = p[n][c] + b[c] + sum_{e in CSR[n]} p[ecol[e]][c]
// Half-wave (32 lanes) per node, register accumulation, no atomics.
// ---------------------------------------------------------------------------
__global__ __launch_bounds__(256) void k_gather(
    const float* __restrict__ p, const float* __restrict__ b,
    const int* __restrict__ start, const int* __restrict__ ecol,
    float* __restrict__ z) {
  int hw = (blockIdx.x * 256 + threadIdx.x) >> 5;
  int c = threadIdx.x & 31;
  if (hw >= N_NODES) return;
  int s = start[hw], e = start[hw + 1];
  float acc = p[(size_t)hw * H_DIM + c] + b[c];
  int i = s;
  for (; i + 1 < e; i += 2) {
    int s0 = ecol[i], s1 = ecol[i + 1];
    float v0 = p[(size_t)s0 * H_DIM + c];
    float v1 = p[(size_t)s1 * H_DIM + c];
    acc += v0;
    acc += v1;
  }
  if (i < e) acc += p[(size_t)ecol[i] * H_DIM + c];
  z[(size_t)hw * H_DIM + c] = acc;
}

// ---------------------------------------------------------------------------
// Fallback (ws too small for CSR): z = p + b, then atomic scatter
// ---------------------------------------------------------------------------
__global__ __launch_bounds__(256) void k_zinit(const float* __restrict__ p,
                                               const float* __restrict__ b,
                                               float* __restrict__ z) {
  int i = blockIdx.x * 256 + threadIdx.x;
  if (i < N_NODES * H_DIM) z[i] = p[i] + b[i & 31];
}

__global__ __launch_bounds__(256) void k_scatter(
    const int* __restrict__ row, const int* __restrict__ col,
    const float* __restrict__ p, float* __restrict__ z) {
  long long t = (long long)blockIdx.x * 256 + threadIdx.x;
  int e = (int)(t >> 5);
  int c = (int)(t & 31);
  if (e < E_EDGES) {
    int s = col[e], d = row[e];
    atomicAdd(&z[(size_t)d * H_DIM + c], p[(size_t)s * H_DIM + c]);
  }
}

// ---------------------------------------------------------------------------
// K3: hpre = relu(z) @ W + b  (N x 32 x 32), fused BN partial sums
// ---------------------------------------------------------------------------
__global__ __launch_bounds__(256) void k_mlp_stats(
    const float* __restrict__ z, const float* __restrict__ W,
    const float* __restrict__ b, float* __restrict__ hpre,
    float* __restrict__ stats) {
  __shared__ float as_[64 * 36];
  __shared__ float ws[32 * 36];
  __shared__ float red[512];
  const int tid = threadIdx.x;
  for (int i = tid; i < 1024; i += 256) {
    int k = i >> 5, c = i & 31;
    ws[c * 36 + k] = W[(size_t)k * H_DIM + c];
  }
  const int r0 = blockIdx.x * 64;
  for (int i = tid; i < 2048; i += 256) {
    int r = i >> 5, c = i & 31;
    int gr = r0 + r;
    float v = (gr < N_NODES) ? z[(size_t)gr * H_DIM + c] : 0.f;
    as_[r * 36 + c] = fmaxf(v, 0.f);
  }
  __syncthreads();
  const int c = tid & 31, rg = tid >> 5;
  float4 wc[8];
  #pragma unroll
  for (int q = 0; q < 8; q++) wc[q] = *(float4*)&ws[c * 36 + q * 4];
  const float bc = b[c];
  float lsum = 0.f, lsq = 0.f;
  #pragma unroll
  for (int i = 0; i < 8; i++) {
    int r = rg * 8 + i;
    float a = bc;
    #pragma unroll
    for (int q = 0; q < 8; q++) {
      float4 h4 = *(float4*)&as_[r * 36 + q * 4];
      a += h4.x * wc[q].x + h4.y * wc[q].y + h4.z * wc[q].z + h4.w * wc[q].w;
    }
    int gr = r0 + r;
    if (gr < N_NODES) {
      hpre[(size_t)gr * H_DIM + c] = a;
      lsum += a; lsq += a * a;
    }
  }
  __syncthreads();
  red[tid] = lsum; red[256 + tid] = lsq;
  __syncthreads();
  if (tid < 32) {
    float s = 0.f, q = 0.f;
    #pragma unroll
    for (int g = 0; g < 8; g++) { s += red[g * 32 + tid]; q += red[256 + g * 32 + tid]; }
    atomicAdd(&stats[tid], s);
    atomicAdd(&stats[32 + tid], q);
  }
}

// ---------------------------------------------------------------------------
// K4: BN finalize -> per-column scale/shift
// ---------------------------------------------------------------------------
__global__ void k_bnfin(const float* __restrict__ stats, const float* __restrict__ g,
                        const float* __restrict__ be, float* __restrict__ ss) {
  int c = threadIdx.x;
  if (c < H_DIM) {
    float m = stats[c] / (float)N_NODES;
    float v = stats[32 + c] / (float)N_NODES - m * m;
    float sc = g[c] * rsqrtf(v + BN_EPS);
    ss[c] = sc;
    ss[32 + c] = be[c] - m * sc;
  }
}

// ---------------------------------------------------------------------------
// K5: p = (hpre*scale+shift) @ W  (N x 32 x 32)
// ---------------------------------------------------------------------------
__global__ __launch_bounds__(256) void k_gemm32_affine(
    const float* __restrict__ hpre, const float* __restrict__ ss,
    const float* __restrict__ W, float* __restrict__ p) {
  __shared__ float hs[64 * 36];
  __shared__ float ws[32 * 36];
  const int tid = threadIdx.x;
  for (int i = tid; i < 1024; i += 256) {
    int k = i >> 5, c = i & 31;
    ws[c * 36 + k] = W[(size_t)k * H_DIM + c];
  }
  const int r0 = blockIdx.x * 64;
  for (int i = tid; i < 2048; i += 256) {
    int r = i >> 5, c = i & 31;
    int gr = r0 + r;
    float v = (gr < N_NODES) ? hpre[(size_t)gr * H_DIM + c] * ss[c] + ss[32 + c] : 0.f;
    hs[r * 36 + c] = v;
  }
  __syncthreads();
  const int c = tid & 31, rg = tid >> 5;
  float4 wc[8];
  #pragma unroll
  for (int q = 0; q < 8; q++) wc[q] = *(float4*)&ws[c * 36 + q * 4];
  #pragma unroll
  for (int i = 0; i < 8; i++) {
    int r = rg * 8 + i;
    float a = 0.f;
    #pragma unroll
    for (int q = 0; q < 8; q++) {
      float4 h4 = *(float4*)&hs[r * 36 + q * 4];
      a += h4.x * wc[q].x + h4.y * wc[q].y + h4.z * wc[q].z + h4.w * wc[q].w;
    }
    int gr = r0 + r;
    if (gr < N_NODES) p[(size_t)gr * H_DIM + c] = a;
  }
}

// ---------------------------------------------------------------------------
// K6: heads: out = relu((hpre*sc+sh)@Wf1 + bf1) @ Wf2 + bf2
// ---------------------------------------------------------------------------
__global__ __launch_bounds__(256) void k_heads(
    const float* __restrict__ hpre, const float* __restrict__ ss,
    const float* __restrict__ W1, const float* __restrict__ b1,
    const float* __restrict__ W2, const float* __restrict__ b2,
    float* __restrict__ out) {
  __shared__ float hs[64 * 36];
  __shared__ float fs[64 * 36];
  __shared__ float w1[32 * 36];
  __shared__ float w2[41 * 36];
  const int tid = threadIdx.x;
  for (int i = tid; i < 1024; i += 256) {
    int k = i >> 5, c = i & 31;
    w1[c * 36 + k] = W1[(size_t)k * H_DIM + c];
  }
  for (int i = tid; i < 41 * 32; i += 256) {
    int j = i >> 5, k = i & 31;
    w2[j * 36 + k] = W2[(size_t)k * C_OUT + j];
  }
  const int r0 = blockIdx.x * 64;
  for (int i = tid; i < 2048; i += 256) {
    int r = i >> 5, c = i & 31;
    int gr = r0 + r;
    hs[r * 36 + c] = (gr < N_NODES) ? hpre[(size_t)gr * H_DIM + c] * ss[c] + ss[32 + c] : 0.f;
  }
  __syncthreads();
  {
    const int c = tid & 31, rg = tid >> 5;
    float4 wc[8];
    #pragma unroll
    for (int q = 0; q < 8; q++) wc[q] = *(float4*)&w1[c * 36 + q * 4];
    const float bc = b1[c];
    #pragma unroll
    for (int i = 0; i < 8; i++) {
      int r = rg * 8 + i;
      float a = bc;
      #pragma unroll
      for (int q = 0; q < 8; q++) {
        float4 h4 = *(float4*)&hs[r * 36 + q * 4];
        a += h4.x * wc[q].x + h4.y * wc[q].y + h4.z * wc[q].z + h4.w * wc[q].w;
      }
      fs[r * 36 + c] = fmaxf(a, 0.f);
    }
  }
  __syncthreads();
  for (int idx = tid; idx < 64 * C_OUT; idx += 256) {
    int r = idx / C_OUT, j = idx - r * C_OUT;
    int gr = r0 + r;
    if (gr < N_NODES) {
      float a = b2[j];
      #pragma unroll
      for (int q = 0; q < 8; q++) {
        float4 f4 = *(float4*)&fs[r * 36 + q * 4];
        float4 w4 = *(float4*)&w2[j * 36 + q * 4];
        a += f4.x * w4.x + f4.y * w4.y + f4.z * w4.z + f4.w * w4.w;
      }
      out[(size_t)gr * C_OUT + j] = a;
    }
  }
}

// ---------------------------------------------------------------------------
extern "C" void kernel_launch(void* const* d_in, const int* in_sizes, int n_in,
                              void* d_out, int out_size, void* d_ws, size_t ws_size,
                              hipStream_t stream) {
  const float* x   = (const float*)d_in[0];
  const int* row   = (const int*)d_in[1];
  const int* col   = (const int*)d_in[2];
  const float* W1a = (const float*)d_in[3];
  const float* b1a = (const float*)d_in[4];
  const float* W1b = (const float*)d_in[5];
  const float* b1b = (const float*)d_in[6];
  const float* g1  = (const float*)d_in[7];
  const float* be1 = (const float*)d_in[8];
  const float* W2a = (const float*)d_in[9];
  const float* b2a = (const float*)d_in[10];
  const float* W2b = (const float*)d_in[11];
  const float* b2b = (const float*)d_in[12];
  const float* g2  = (const float*)d_in[13];
  const float* be2 = (const float*)d_in[14];
  const float* Wf1 = (const float*)d_in[15];
  const float* bf1 = (const float*)d_in[16];
  const float* Wf2 = (const float*)d_in[17];
  const float* bf2 = (const float*)d_in[18];
  float* out = (float*)d_out;

  float* ws = (float*)d_ws;
  const size_t NH = (size_t)N_NODES * H_DIM;       // 1.6M
  float* pA    = ws;
  float* zB    = ws + NH;
  float* hC    = ws + 2 * NH;
  float* stats = ws + 3 * NH;                      // 256 floats
  int*   startA = (int*)(ws + 3 * NH + 256);        // N+1 (pad 50016)
  int*   cursor = startA + 50016;                   // N
  int*   deg    = cursor + 50016;                   // N
  int*   ecol   = deg + 50016;                      // E
  int*   bsum   = ecol + E_EDGES;                   // 256
  int*   boff   = bsum + 256;                       // 256
  const size_t need_bytes = ((3 * NH + 256) + 3 * 50016 + E_EDGES + 512) * 4;
  const bool use_csr = (ws_size >= need_bytes);

  hipMemsetAsync(stats, 0, 256 * sizeof(float), stream);

  const int g64   = (N_NODES + 63) / 64;           // 782
  const int gE    = (E_EDGES + 255) / 256;         // 3125
  const int gN    = (N_NODES + 255) / 256;         // 196
  const int gHW   = (N_NODES * 32 + 255) / 256;    // 6250
  const int gScat = (E_EDGES * 32 + 255) / 256;    // 100000

  if (use_csr) {
    hipMemsetAsync(deg, 0, 50000 * sizeof(int), stream);
    k_hist <<<gE, 256, 0, stream>>>(row, deg);
    k_scanA<<<gN, 256, 0, stream>>>(deg, startA, bsum);
    k_scanB<<<1, 256, 0, stream>>>(bsum, boff, gN);
    k_scanC<<<gN, 256, 0, stream>>>(startA, boff, cursor);
    k_fill <<<gE, 256, 0, stream>>>(row, col, cursor, ecol);
  }

  // conv1
  k_gemm_in_v2<<<GEMM_GRID, 256, 0, stream>>>(x, W1a, pA);
  if (use_csr) {
    k_gather<<<gHW, 256, 0, stream>>>(pA, b1a, startA, ecol, zB);
  } else {
    k_zinit<<<g64 * 8, 256, 0, stream>>>(pA, b1a, zB);
    k_scatter<<<gScat, 256, 0, stream>>>(row, col, pA, zB);
  }
  k_mlp_stats<<<g64, 256, 0, stream>>>(zB, W1b, b1b, hC, stats);
  k_bnfin<<<1, 64, 0, stream>>>(stats, g1, be1, stats + 64);
  // conv2
  k_gemm32_affine<<<g64, 256, 0, stream>>>(hC, stats + 64, W2a, pA);
  if (use_csr) {
    k_gather<<<gHW, 256, 0, stream>>>(pA, b2a, startA, ecol, zB);
  } else {
    k_zinit<<<g64 * 8, 256, 0, stream>>>(pA, b2a, zB);
    k_scatter<<<gScat, 256, 0, stream>>>(row, col, pA, zB);
  }
  k_mlp_stats<<<g64, 256, 0, stream>>>(zB, W2b, b2b, hC, stats + 128);
  k_bnfin<<<1, 64, 0, stream>>>(stats + 128, g2, be2, stats + 192);
  // heads
  k_heads<<<g64, 256, 0, stream>>>(hC, stats + 192, Wf1, bf1, Wf2, bf2, out);
}

// Round 3
// 483.835 us; speedup vs baseline: 1.3006x; 1.3006x over previous
//
#include <hip/hip_runtime.h>
#include <hip/hip_bf16.h>

#define N_NODES 50000
#define F_IN    602
#define H_DIM   32
#define C_OUT   41
#define E_EDGES 800000
#define BN_EPS  1e-5f

// ---------------------------------------------------------------------------
// K1 v3: p = x @ W1a  (N x 602 x 32).
// 64-row tiles (782 blocks ~ 3/CU), BK=64 chunks, coalesced staging,
// single LDS buffer + REGISTER PREFETCH: next chunk's global loads issue
// before computing current chunk, so memory latency hides under ~3k cyc
// of FMA work. LDS 26 KB -> 6 blocks/CU capacity.
// Microtile 4 rows x 2 cols per thread, float4 over k, conflict-free pitch 68.
// ---------------------------------------------------------------------------
__global__ __launch_bounds__(256) void k_gemm_in_v3(
    const float* __restrict__ x, const float* __restrict__ W,
    float* __restrict__ p) {
  __shared__ float xs[64 * 68];
  __shared__ float ws[32 * 68];
  const int tid = threadIdx.x;
  const int r0 = blockIdx.x * 64;

  // compute mapping: rows rgg+16i (i<4), cols cg+16j (j<2)
  const int cg  = tid & 15;
  const int rgg = tid >> 4;

  // staging mapping: pass pp -> row pp*8 + srow, float2 slot fe
  const int srow = tid >> 5;
  const int fe   = tid & 31;

  // fixed row pointers for this thread's staging rows (clamped)
  const float* xrp[8];
  #pragma unroll
  for (int pp = 0; pp < 8; pp++) {
    int rr = r0 + pp * 8 + srow;
    if (rr > N_NODES - 1) rr = N_NODES - 1;
    xrp[pp] = x + (size_t)rr * F_IN;
  }

  float2 xr[8];
  float4 wr[2];

  // prefetch chunk 0 (always fully in-bounds: k < 64 <= 602)
  #pragma unroll
  for (int pp = 0; pp < 8; pp++)
    xr[pp] = *(const float2*)(xrp[pp] + 2 * fe);
  #pragma unroll
  for (int q = 0; q < 2; q++)
    wr[q] = *(const float4*)(W + q * 1024 + 4 * tid);

  float acc[4][2] = {};

  for (int ch = 0; ch < 10; ch++) {
    __syncthreads();                       // LDS consumers of prev chunk done
    // regs -> LDS
    #pragma unroll
    for (int pp = 0; pp < 8; pp++)
      *(float2*)&xs[(pp * 8 + srow) * 68 + 2 * fe] = xr[pp];
    #pragma unroll
    for (int q = 0; q < 2; q++) {
      int off = q * 1024 + 4 * tid;        // float offset inside chunk
      int kk = off >> 5, c0 = off & 31;    // W chunk is [kk][c] row-major
      ws[(c0 + 0) * 68 + kk] = wr[q].x;
      ws[(c0 + 1) * 68 + kk] = wr[q].y;
      ws[(c0 + 2) * 68 + kk] = wr[q].z;
      ws[(c0 + 3) * 68 + kk] = wr[q].w;
    }
    __syncthreads();
    // issue next chunk's loads NOW; they drain during compute below
    if (ch < 9) {
      const int k0 = (ch + 1) * 64;
      #pragma unroll
      for (int pp = 0; pp < 8; pp++) {
        int k = k0 + 2 * fe;
        float2 v = {0.f, 0.f};
        if (k + 2 <= F_IN) v = *(const float2*)(xrp[pp] + k);
        xr[pp] = v;
      }
      #pragma unroll
      for (int q = 0; q < 2; q++) {
        int off = k0 * H_DIM + q * 1024 + 4 * tid;
        float4 v = {0.f, 0.f, 0.f, 0.f};
        if (off < F_IN * H_DIM) v = *(const float4*)(W + off);
        wr[q] = v;
      }
    }
    // compute current chunk from LDS
    #pragma unroll
    for (int kq = 0; kq < 16; kq++) {
      float4 xv[4], wv[2];
      #pragma unroll
      for (int i = 0; i < 4; i++) xv[i] = *(float4*)&xs[(rgg + 16 * i) * 68 + kq * 4];
      #pragma unroll
      for (int j = 0; j < 2; j++) wv[j] = *(float4*)&ws[(cg + 16 * j) * 68 + kq * 4];
      #pragma unroll
      for (int i = 0; i < 4; i++)
        #pragma unroll
        for (int j = 0; j < 2; j++)
          acc[i][j] += xv[i].x * wv[j].x + xv[i].y * wv[j].y +
                       xv[i].z * wv[j].z + xv[i].w * wv[j].w;
    }
  }

  #pragma unroll
  for (int i = 0; i < 4; i++) {
    int gr = r0 + rgg + 16 * i;
    if (gr < N_NODES) {
      #pragma unroll
      for (int j = 0; j < 2; j++)
        p[(size_t)gr * H_DIM + cg + 16 * j] = acc[i][j];
    }
  }
}

// ---------------------------------------------------------------------------
// CSR build: histogram -> 3-kernel exclusive scan -> fill
// ---------------------------------------------------------------------------
__global__ __launch_bounds__(256) void k_hist(const int* __restrict__ row,
                                              int* __restrict__ deg) {
  int e = blockIdx.x * 256 + threadIdx.x;
  if (e < E_EDGES) atomicAdd(&deg[row[e]], 1);
}

__global__ __launch_bounds__(256) void k_scanA(const int* __restrict__ deg,
                                               int* __restrict__ start,
                                               int* __restrict__ bsum) {
  __shared__ int sc[256];
  int t = threadIdx.x, i = blockIdx.x * 256 + t;
  int v = (i < N_NODES) ? deg[i] : 0;
  sc[t] = v;
  __syncthreads();
  #pragma unroll
  for (int off = 1; off < 256; off <<= 1) {
    int u = (t >= off) ? sc[t - off] : 0;
    __syncthreads();
    sc[t] += u;
    __syncthreads();
  }
  if (i < N_NODES) start[i] = sc[t] - v;
  if (t == 255) bsum[blockIdx.x] = sc[255];
}

__global__ __launch_bounds__(256) void k_scanB(const int* __restrict__ bsum,
                                               int* __restrict__ boff, int nb) {
  __shared__ int sc[256];
  int t = threadIdx.x;
  int v = (t < nb) ? bsum[t] : 0;
  sc[t] = v;
  __syncthreads();
  #pragma unroll
  for (int off = 1; off < 256; off <<= 1) {
    int u = (t >= off) ? sc[t - off] : 0;
    __syncthreads();
    sc[t] += u;
    __syncthreads();
  }
  if (t < nb) boff[t] = sc[t] - v;
}

__global__ __launch_bounds__(256) void k_scanC(int* __restrict__ start,
                                               const int* __restrict__ boff,
                                               int* __restrict__ cursor) {
  int i = blockIdx.x * 256 + threadIdx.x;
  if (i < N_NODES) {
    int s = start[i] + boff[blockIdx.x];
    start[i] = s;
    cursor[i] = s;
  }
  if (i == 0) start[N_NODES] = E_EDGES;
}

__global__ __launch_bounds__(256) void k_fill(const int* __restrict__ row,
                                              const int* __restrict__ col,
                                              int* __restrict__ cursor,
                                              int* __restrict__ ecol) {
  int e = blockIdx.x * 256 + threadIdx.x;
  if (e < E_EDGES) {
    int pos = atomicAdd(&cursor[row[e]], 1);
    ecol[pos] = col[e];
  }
}

// ---------------------------------------------------------------------------
// Gather-aggregate: z[n][c] = p[n][c] + b[c] + sum_{e in CSR[n]} p[ecol[e]][c]
// Half-wave per node; unroll 4 for independent loads in flight.
// ---------------------------------------------------------------------------
__global__ __launch_bounds__(256) void k_gather(
    const float* __restrict__ p, const float* __restrict__ b,
    const int* __restrict__ start, const int* __restrict__ ecol,
    float* __restrict__ z) {
  int hw = (blockIdx.x * 256 + threadIdx.x) >> 5;
  int c = threadIdx.x & 31;
  if (hw >= N_NODES) return;
  int s = start[hw], e = start[hw + 1];
  float acc = p[(size_t)hw * H_DIM + c] + b[c];
  int i = s;
  for (; i + 3 < e; i += 4) {
    int s0 = ecol[i], s1 = ecol[i + 1], s2 = ecol[i + 2], s3 = ecol[i + 3];
    float v0 = p[(size_t)s0 * H_DIM + c];
    float v1 = p[(size_t)s1 * H_DIM + c];
    float v2 = p[(size_t)s2 * H_DIM + c];
    float v3 = p[(size_t)s3 * H_DIM + c];
    acc += v0; acc += v1; acc += v2; acc += v3;
  }
  for (; i < e; i++) acc += p[(size_t)ecol[i] * H_DIM + c];
  z[(size_t)hw * H_DIM + c] = acc;
}

// ---------------------------------------------------------------------------
// Fallback (ws too small for CSR): z = p + b, then atomic scatter
// ---------------------------------------------------------------------------
__global__ __launch_bounds__(256) void k_zinit(const float* __restrict__ p,
                                               const float* __restrict__ b,
                                               float* __restrict__ z) {
  int i = blockIdx.x * 256 + threadIdx.x;
  if (i < N_NODES * H_DIM) z[i] = p[i] + b[i & 31];
}

__global__ __launch_bounds__(256) void k_scatter(
    const int* __restrict__ row, const int* __restrict__ col,
    const float* __restrict__ p, float* __restrict__ z) {
  long long t = (long long)blockIdx.x * 256 + threadIdx.x;
  int e = (int)(t >> 5);
  int c = (int)(t & 31);
  if (e < E_EDGES) {
    int s = col[e], d = row[e];
    atomicAdd(&z[(size_t)d * H_DIM + c], p[(size_t)s * H_DIM + c]);
  }
}

// ---------------------------------------------------------------------------
// K3: hpre = relu(z) @ W + b  (N x 32 x 32), fused BN partial sums
// stats out: [0..31]=sum, [32..63]=sumsq (pre-zeroed)
// ---------------------------------------------------------------------------
__global__ __launch_bounds__(256) void k_mlp_stats(
    const float* __restrict__ z, const float* __restrict__ W,
    const float* __restrict__ b, float* __restrict__ hpre,
    float* __restrict__ stats) {
  __shared__ float as_[64 * 36];
  __shared__ float ws[32 * 36];
  __shared__ float red[512];
  const int tid = threadIdx.x;
  for (int i = tid; i < 1024; i += 256) {
    int k = i >> 5, c = i & 31;
    ws[c * 36 + k] = W[(size_t)k * H_DIM + c];
  }
  const int r0 = blockIdx.x * 64;
  for (int i = tid; i < 2048; i += 256) {
    int r = i >> 5, c = i & 31;
    int gr = r0 + r;
    float v = (gr < N_NODES) ? z[(size_t)gr * H_DIM + c] : 0.f;
    as_[r * 36 + c] = fmaxf(v, 0.f);
  }
  __syncthreads();
  const int c = tid & 31, rg = tid >> 5;
  float4 wc[8];
  #pragma unroll
  for (int q = 0; q < 8; q++) wc[q] = *(float4*)&ws[c * 36 + q * 4];
  const float bc = b[c];
  float lsum = 0.f, lsq = 0.f;
  #pragma unroll
  for (int i = 0; i < 8; i++) {
    int r = rg * 8 + i;
    float a = bc;
    #pragma unroll
    for (int q = 0; q < 8; q++) {
      float4 h4 = *(float4*)&as_[r * 36 + q * 4];
      a += h4.x * wc[q].x + h4.y * wc[q].y + h4.z * wc[q].z + h4.w * wc[q].w;
    }
    int gr = r0 + r;
    if (gr < N_NODES) {
      hpre[(size_t)gr * H_DIM + c] = a;
      lsum += a; lsq += a * a;
    }
  }
  __syncthreads();
  red[tid] = lsum; red[256 + tid] = lsq;
  __syncthreads();
  if (tid < 32) {
    float s = 0.f, q = 0.f;
    #pragma unroll
    for (int g = 0; g < 8; g++) { s += red[g * 32 + tid]; q += red[256 + g * 32 + tid]; }
    atomicAdd(&stats[tid], s);
    atomicAdd(&stats[32 + tid], q);
  }
}

// ---------------------------------------------------------------------------
// K5: p = BN(hpre) @ W  -- BN finalize folded in (computed from raw stats)
// ---------------------------------------------------------------------------
__global__ __launch_bounds__(256) void k_gemm32_affine(
    const float* __restrict__ hpre, const float* __restrict__ stats,
    const float* __restrict__ g, const float* __restrict__ be,
    const float* __restrict__ W, float* __restrict__ p) {
  __shared__ float hs[64 * 36];
  __shared__ float ws[32 * 36];
  __shared__ float ssl[64];
  const int tid = threadIdx.x;
  if (tid < 32) {
    float m = stats[tid] * (1.f / N_NODES);
    float v = stats[32 + tid] * (1.f / N_NODES) - m * m;
    float sc = g[tid] * rsqrtf(v + BN_EPS);
    ssl[tid] = sc;
    ssl[32 + tid] = be[tid] - m * sc;
  }
  for (int i = tid; i < 1024; i += 256) {
    int k = i >> 5, c = i & 31;
    ws[c * 36 + k] = W[(size_t)k * H_DIM + c];
  }
  __syncthreads();
  const int r0 = blockIdx.x * 64;
  for (int i = tid; i < 2048; i += 256) {
    int r = i >> 5, c = i & 31;
    int gr = r0 + r;
    float v = (gr < N_NODES) ? hpre[(size_t)gr * H_DIM + c] * ssl[c] + ssl[32 + c] : 0.f;
    hs[r * 36 + c] = v;
  }
  __syncthreads();
  const int c = tid & 31, rg = tid >> 5;
  float4 wc[8];
  #pragma unroll
  for (int q = 0; q < 8; q++) wc[q] = *(float4*)&ws[c * 36 + q * 4];
  #pragma unroll
  for (int i = 0; i < 8; i++) {
    int r = rg * 8 + i;
    float a = 0.f;
    #pragma unroll
    for (int q = 0; q < 8; q++) {
      float4 h4 = *(float4*)&hs[r * 36 + q * 4];
      a += h4.x * wc[q].x + h4.y * wc[q].y + h4.z * wc[q].z + h4.w * wc[q].w;
    }
    int gr = r0 + r;
    if (gr < N_NODES) p[(size_t)gr * H_DIM + c] = a;
  }
}

// ---------------------------------------------------------------------------
// K6: heads: out = relu(BN(hpre)@Wf1 + bf1) @ Wf2 + bf2 (BN folded in)
// ---------------------------------------------------------------------------
__global__ __launch_bounds__(256) void k_heads(
    const float* __restrict__ hpre, const float* __restrict__ stats,
    const float* __restrict__ g, const float* __restrict__ be,
    const float* __restrict__ W1, const float* __restrict__ b1,
    const float* __restrict__ W2, const float* __restrict__ b2,
    float* __restrict__ out) {
  __shared__ float hs[64 * 36];
  __shared__ float fs[64 * 36];
  __shared__ float w1[32 * 36];
  __shared__ float w2[41 * 36];
  __shared__ float ssl[64];
  const int tid = threadIdx.x;
  if (tid < 32) {
    float m = stats[tid] * (1.f / N_NODES);
    float v = stats[32 + tid] * (1.f / N_NODES) - m * m;
    float sc = g[tid] * rsqrtf(v + BN_EPS);
    ssl[tid] = sc;
    ssl[32 + tid] = be[tid] - m * sc;
  }
  for (int i = tid; i < 1024; i += 256) {
    int k = i >> 5, c = i & 31;
    w1[c * 36 + k] = W1[(size_t)k * H_DIM + c];
  }
  for (int i = tid; i < 41 * 32; i += 256) {
    int j = i >> 5, k = i & 31;
    w2[j * 36 + k] = W2[(size_t)k * C_OUT + j];
  }
  __syncthreads();
  const int r0 = blockIdx.x * 64;
  for (int i = tid; i < 2048; i += 256) {
    int r = i >> 5, c = i & 31;
    int gr = r0 + r;
    hs[r * 36 + c] = (gr < N_NODES) ? hpre[(size_t)gr * H_DIM + c] * ssl[c] + ssl[32 + c] : 0.f;
  }
  __syncthreads();
  {
    const int c = tid & 31, rg = tid >> 5;
    float4 wc[8];
    #pragma unroll
    for (int q = 0; q < 8; q++) wc[q] = *(float4*)&w1[c * 36 + q * 4];
    const float bc = b1[c];
    #pragma unroll
    for (int i = 0; i < 8; i++) {
      int r = rg * 8 + i;
      float a = bc;
      #pragma unroll
      for (int q = 0; q < 8; q++) {
        float4 h4 = *(float4*)&hs[r * 36 + q * 4];
        a += h4.x * wc[q].x + h4.y * wc[q].y + h4.z * wc[q].z + h4.w * wc[q].w;
      }
      fs[r * 36 + c] = fmaxf(a, 0.f);
    }
  }
  __syncthreads();
  for (int idx = tid; idx < 64 * C_OUT; idx += 256) {
    int r = idx / C_OUT, j = idx - r * C_OUT;
    int gr = r0 + r;
    if (gr < N_NODES) {
      float a = b2[j];
      #pragma unroll
      for (int q = 0; q < 8; q++) {
        float4 f4 = *(float4*)&fs[r * 36 + q * 4];
        float4 w4 = *(float4*)&w2[j * 36 + q * 4];
        a += f4.x * w4.x + f4.y * w4.y + f4.z * w4.z + f4.w * w4.w;
      }
      out[(size_t)gr * C_OUT + j] = a;
    }
  }
}

// ---------------------------------------------------------------------------
extern "C" void kernel_launch(void* const* d_in, const int* in_sizes, int n_in,
                              void* d_out, int out_size, void* d_ws, size_t ws_size,
                              hipStream_t stream) {
  const float* x   = (const float*)d_in[0];
  const int* row   = (const int*)d_in[1];
  const int* col   = (const int*)d_in[2];
  const float* W1a = (const float*)d_in[3];
  const float* b1a = (const float*)d_in[4];
  const float* W1b = (const float*)d_in[5];
  const float* b1b = (const float*)d_in[6];
  const float* g1  = (const float*)d_in[7];
  const float* be1 = (const float*)d_in[8];
  const float* W2a = (const float*)d_in[9];
  const float* b2a = (const float*)d_in[10];
  const float* W2b = (const float*)d_in[11];
  const float* b2b = (const float*)d_in[12];
  const float* g2  = (const float*)d_in[13];
  const float* be2 = (const float*)d_in[14];
  const float* Wf1 = (const float*)d_in[15];
  const float* bf1 = (const float*)d_in[16];
  const float* Wf2 = (const float*)d_in[17];
  const float* bf2 = (const float*)d_in[18];
  float* out = (float*)d_out;

  float* ws = (float*)d_ws;
  const size_t NH = (size_t)N_NODES * H_DIM;        // 1.6M
  float* pA    = ws;
  float* zB    = ws + NH;
  float* hC    = ws + 2 * NH;
  float* stats = ws + 3 * NH;                       // 128 floats (2 layers)
  int*   startA = (int*)(ws + 3 * NH + 256);        // N+1 (pad 50016)
  int*   cursor = startA + 50016;                   // N
  int*   deg    = cursor + 50016;                   // N
  int*   ecol   = deg + 50016;                      // E
  int*   bsum   = ecol + E_EDGES;                   // 256
  int*   boff   = bsum + 256;                       // 256
  const size_t need_bytes = ((3 * NH + 256) + 3 * 50016 + E_EDGES + 512) * 4;
  const bool use_csr = (ws_size >= need_bytes);

  hipMemsetAsync(stats, 0, 128 * sizeof(float), stream);

  const int g64   = (N_NODES + 63) / 64;            // 782
  const int gE    = (E_EDGES + 255) / 256;          // 3125
  const int gN    = (N_NODES + 255) / 256;          // 196
  const int gHW   = (N_NODES * 32 + 255) / 256;     // 6250
  const int gScat = (E_EDGES * 32 + 255) / 256;     // 100000

  if (use_csr) {
    hipMemsetAsync(deg, 0, 50000 * sizeof(int), stream);
    k_hist <<<gE, 256, 0, stream>>>(row, deg);
    k_scanA<<<gN, 256, 0, stream>>>(deg, startA, bsum);
    k_scanB<<<1, 256, 0, stream>>>(bsum, boff, gN);
    k_scanC<<<gN, 256, 0, stream>>>(startA, boff, cursor);
    k_fill <<<gE, 256, 0, stream>>>(row, col, cursor, ecol);
  }

  // conv1
  k_gemm_in_v3<<<g64, 256, 0, stream>>>(x, W1a, pA);
  if (use_csr) {
    k_gather<<<gHW, 256, 0, stream>>>(pA, b1a, startA, ecol, zB);
  } else {
    k_zinit<<<g64 * 8, 256, 0, stream>>>(pA, b1a, zB);
    k_scatter<<<gScat, 256, 0, stream>>>(row, col, pA, zB);
  }
  k_mlp_stats<<<g64, 256, 0, stream>>>(zB, W1b, b1b, hC, stats);
  // conv2 (BN1 folded into the GEMM)
  k_gemm32_affine<<<g64, 256, 0, stream>>>(hC, stats, g1, be1, W2a, pA);
  if (use_csr) {
    k_gather<<<gHW, 256, 0, stream>>>(pA, b2a, startA, ecol, zB);
  } else {
    k_zinit<<<g64 * 8, 256, 0, stream>>>(pA, b2a, zB);
    k_scatter<<<gScat, 256, 0, stream>>>(row, col, pA, zB);
  }
  k_mlp_stats<<<g64, 256, 0, stream>>>(zB, W2b, b2b, hC, stats + 64);
  // heads (BN2 folded in)
  k_heads<<<g64, 256, 0, stream>>>(hC, stats + 64, g2, be2, Wf1, bf1, Wf2, bf2, out);
}

// Round 4
// 462.504 us; speedup vs baseline: 1.3606x; 1.0461x over previous
//
#include <hip/hip_runtime.h>
#include <hip/hip_bf16.h>

#define N_NODES 50000
#define F_IN    602
#define H_DIM   32
#define C_OUT   41
#define E_EDGES 800000
#define BN_EPS  1e-5f

typedef short bf16x8 __attribute__((ext_vector_type(8)));
typedef float f32x4  __attribute__((ext_vector_type(4)));

__device__ inline unsigned short f2bf(float f) {
  unsigned int u = __builtin_bit_cast(unsigned int, f);
  unsigned int r = (u + 0x7FFFu + ((u >> 16) & 1u)) >> 16;
  return (unsigned short)r;
}

// ---------------------------------------------------------------------------
// K1 v4: p = x @ W1a via split-bf16 MFMA (xh*wh + xl*wh + xh*wl).
// 64-row tile, 256 thr (4 waves), wave = 16 rows x 32 cols (2 n-tiles).
// LDS: xh/xl [64][40] ushort, wh/wl [32][40] ushort (15.4 KB). BK=32, 19 chunks.
// Register prefetch of next chunk; 2 barriers/chunk.
// ---------------------------------------------------------------------------
__global__ __launch_bounds__(256) void k_gemm_mfma(
    const float* __restrict__ x, const float* __restrict__ W,
    float* __restrict__ p) {
  __shared__ unsigned short xh[64 * 40], xl[64 * 40];
  __shared__ unsigned short wh[32 * 40], wl[32 * 40];
  const int tid = threadIdx.x;
  const int wv = tid >> 6, ln = tid & 63;
  const int m = ln & 15, q = ln >> 4;       // MFMA lane decomposition
  const int r0 = blockIdx.x * 64;

  // staging indices: x as float2, rows srow+16p, k-slot 2*ks2
  const int srow = tid >> 4, ks2 = tid & 15;
  // W staging: one float4 = W[k0+wk][4*c4 .. +3]
  const int wk = tid >> 3, c4 = tid & 7;

  float2 xr[4];
  float4 wr;

  auto prefetch = [&](int k0) {
    #pragma unroll
    for (int pp = 0; pp < 4; pp++) {
      int rr = r0 + srow + 16 * pp;
      int k = k0 + 2 * ks2;
      float2 v = {0.f, 0.f};
      if (rr < N_NODES && k <= F_IN - 2) v = *(const float2*)(x + (size_t)rr * F_IN + k);
      xr[pp] = v;
    }
    {
      int k = k0 + wk;
      float4 v = {0.f, 0.f, 0.f, 0.f};
      if (k < F_IN) v = *(const float4*)(W + (size_t)k * H_DIM + 4 * c4);
      wr = v;
    }
  };

  f32x4 acc0 = {0.f, 0.f, 0.f, 0.f};
  f32x4 acc1 = {0.f, 0.f, 0.f, 0.f};

  prefetch(0);

  unsigned int* xh32 = (unsigned int*)xh;
  unsigned int* xl32 = (unsigned int*)xl;

  for (int ch = 0; ch < 19; ch++) {
    __syncthreads();                    // prior chunk's LDS consumers done
    // regs -> LDS (split to bf16 hi/lo)
    #pragma unroll
    for (int pp = 0; pp < 4; pp++) {
      int row = srow + 16 * pp;
      float2 v = xr[pp];
      unsigned short h0 = f2bf(v.x), h1 = f2bf(v.y);
      float f0 = __builtin_bit_cast(float, (unsigned int)h0 << 16);
      float f1 = __builtin_bit_cast(float, (unsigned int)h1 << 16);
      unsigned short l0 = f2bf(v.x - f0), l1 = f2bf(v.y - f1);
      xh32[row * 20 + ks2] = (unsigned int)h0 | ((unsigned int)h1 << 16);
      xl32[row * 20 + ks2] = (unsigned int)l0 | ((unsigned int)l1 << 16);
    }
    {
      float wf[4] = {wr.x, wr.y, wr.z, wr.w};
      #pragma unroll
      for (int i = 0; i < 4; i++) {
        unsigned short hh = f2bf(wf[i]);
        float fh = __builtin_bit_cast(float, (unsigned int)hh << 16);
        unsigned short ll = f2bf(wf[i] - fh);
        wh[(4 * c4 + i) * 40 + wk] = hh;
        wl[(4 * c4 + i) * 40 + wk] = ll;
      }
    }
    __syncthreads();
    if (ch < 18) prefetch((ch + 1) * 32);

    // MFMA compute: A row = 16*wv + m, k = q*8+j; B col = m (+16), k = q*8+j
    const int abase = (16 * wv + m) * 40 + q * 8;
    const int bbase = m * 40 + q * 8;
    bf16x8 axh = *(const bf16x8*)&xh[abase];
    bf16x8 axl = *(const bf16x8*)&xl[abase];
    bf16x8 b0h = *(const bf16x8*)&wh[bbase];
    bf16x8 b0l = *(const bf16x8*)&wl[bbase];
    bf16x8 b1h = *(const bf16x8*)&wh[bbase + 16 * 40];
    bf16x8 b1l = *(const bf16x8*)&wl[bbase + 16 * 40];
    acc0 = __builtin_amdgcn_mfma_f32_16x16x32_bf16(axh, b0h, acc0, 0, 0, 0);
    acc1 = __builtin_amdgcn_mfma_f32_16x16x32_bf16(axh, b1h, acc1, 0, 0, 0);
    acc0 = __builtin_amdgcn_mfma_f32_16x16x32_bf16(axl, b0h, acc0, 0, 0, 0);
    acc1 = __builtin_amdgcn_mfma_f32_16x16x32_bf16(axl, b1h, acc1, 0, 0, 0);
    acc0 = __builtin_amdgcn_mfma_f32_16x16x32_bf16(axh, b0l, acc0, 0, 0, 0);
    acc1 = __builtin_amdgcn_mfma_f32_16x16x32_bf16(axh, b1l, acc1, 0, 0, 0);
  }

  // C/D: col = lane&15, row = (lane>>4)*4 + reg
  #pragma unroll
  for (int reg = 0; reg < 4; reg++) {
    int rowg = r0 + 16 * wv + q * 4 + reg;
    if (rowg < N_NODES) {
      p[(size_t)rowg * H_DIM + m]      = acc0[reg];
      p[(size_t)rowg * H_DIM + m + 16] = acc1[reg];
    }
  }
}

// ---------------------------------------------------------------------------
// CSR build: histogram -> 3-kernel exclusive scan -> fill
// ---------------------------------------------------------------------------
__global__ __launch_bounds__(256) void k_hist(const int* __restrict__ row,
                                              int* __restrict__ deg) {
  int e = blockIdx.x * 256 + threadIdx.x;
  if (e < E_EDGES) atomicAdd(&deg[row[e]], 1);
}

__global__ __launch_bounds__(256) void k_scanA(const int* __restrict__ deg,
                                               int* __restrict__ start,
                                               int* __restrict__ bsum) {
  __shared__ int sc[256];
  int t = threadIdx.x, i = blockIdx.x * 256 + t;
  int v = (i < N_NODES) ? deg[i] : 0;
  sc[t] = v;
  __syncthreads();
  #pragma unroll
  for (int off = 1; off < 256; off <<= 1) {
    int u = (t >= off) ? sc[t - off] : 0;
    __syncthreads();
    sc[t] += u;
    __syncthreads();
  }
  if (i < N_NODES) start[i] = sc[t] - v;
  if (t == 255) bsum[blockIdx.x] = sc[255];
}

__global__ __launch_bounds__(256) void k_scanB(const int* __restrict__ bsum,
                                               int* __restrict__ boff, int nb) {
  __shared__ int sc[256];
  int t = threadIdx.x;
  int v = (t < nb) ? bsum[t] : 0;
  sc[t] = v;
  __syncthreads();
  #pragma unroll
  for (int off = 1; off < 256; off <<= 1) {
    int u = (t >= off) ? sc[t - off] : 0;
    __syncthreads();
    sc[t] += u;
    __syncthreads();
  }
  if (t < nb) boff[t] = sc[t] - v;
}

__global__ __launch_bounds__(256) void k_scanC(int* __restrict__ start,
                                               const int* __restrict__ boff,
                                               int* __restrict__ cursor) {
  int i = blockIdx.x * 256 + threadIdx.x;
  if (i < N_NODES) {
    int s = start[i] + boff[blockIdx.x];
    start[i] = s;
    cursor[i] = s;
  }
  if (i == 0) start[N_NODES] = E_EDGES;
}

__global__ __launch_bounds__(256) void k_fill(const int* __restrict__ row,
                                              const int* __restrict__ col,
                                              int* __restrict__ cursor,
                                              int* __restrict__ ecol) {
  int e = blockIdx.x * 256 + threadIdx.x;
  if (e < E_EDGES) {
    int pos = atomicAdd(&cursor[row[e]], 1);
    ecol[pos] = col[e];
  }
}

// ---------------------------------------------------------------------------
// Fused: gather-aggregate (CSR) -> relu -> 32x32 GEMM -> BN partial sums.
// Block = 64 nodes; half-wave per node (8 nodes sequential per half-wave).
// z never hits global memory.
// ---------------------------------------------------------------------------
__global__ __launch_bounds__(256) void k_gather_mlp(
    const float* __restrict__ p, const float* __restrict__ bagg,
    const int* __restrict__ start, const int* __restrict__ ecol,
    const float* __restrict__ Wm, const float* __restrict__ bm,
    float* __restrict__ hpre, float* __restrict__ stats) {
  __shared__ float as_[64 * 36];
  __shared__ float ws[32 * 36];
  __shared__ float red[512];
  const int tid = threadIdx.x;
  for (int i = tid; i < 1024; i += 256) {
    int k = i >> 5, c = i & 31;
    ws[c * 36 + k] = Wm[(size_t)k * H_DIM + c];
  }
  const int hw = tid >> 5, c = tid & 31;
  const int n0 = blockIdx.x * 64;
  const float bca = bagg[c];
  for (int s = 0; s < 8; s++) {
    int lr = hw * 8 + s;
    int n = n0 + lr;
    float acc = 0.f;
    if (n < N_NODES) {
      acc = p[(size_t)n * H_DIM + c] + bca;
      int i0 = start[n], i1 = start[n + 1];
      int i = i0;
      for (; i + 3 < i1; i += 4) {
        int s0 = ecol[i], s1 = ecol[i + 1], s2 = ecol[i + 2], s3 = ecol[i + 3];
        float v0 = p[(size_t)s0 * H_DIM + c];
        float v1 = p[(size_t)s1 * H_DIM + c];
        float v2 = p[(size_t)s2 * H_DIM + c];
        float v3 = p[(size_t)s3 * H_DIM + c];
        acc += v0; acc += v1; acc += v2; acc += v3;
      }
      for (; i < i1; i++) acc += p[(size_t)ecol[i] * H_DIM + c];
      acc = fmaxf(acc, 0.f);   // relu(z)
    }
    as_[lr * 36 + c] = acc;
  }
  __syncthreads();
  const int rg = tid >> 5;
  float4 wc[8];
  #pragma unroll
  for (int qq = 0; qq < 8; qq++) wc[qq] = *(float4*)&ws[c * 36 + qq * 4];
  const float bc = bm[c];
  float lsum = 0.f, lsq = 0.f;
  #pragma unroll
  for (int i = 0; i < 8; i++) {
    int r = rg * 8 + i;
    float a = bc;
    #pragma unroll
    for (int qq = 0; qq < 8; qq++) {
      float4 h4 = *(float4*)&as_[r * 36 + qq * 4];
      a += h4.x * wc[qq].x + h4.y * wc[qq].y + h4.z * wc[qq].z + h4.w * wc[qq].w;
    }
    int gr = n0 + r;
    if (gr < N_NODES) {
      hpre[(size_t)gr * H_DIM + c] = a;
      lsum += a; lsq += a * a;
    }
  }
  __syncthreads();
  red[tid] = lsum; red[256 + tid] = lsq;
  __syncthreads();
  if (tid < 32) {
    float s = 0.f, qv = 0.f;
    #pragma unroll
    for (int g = 0; g < 8; g++) { s += red[g * 32 + tid]; qv += red[256 + g * 32 + tid]; }
    atomicAdd(&stats[tid], s);
    atomicAdd(&stats[32 + tid], qv);
  }
}

// ---------------------------------------------------------------------------
// Fallback path (ws too small for CSR)
// ---------------------------------------------------------------------------
__global__ __launch_bounds__(256) void k_zinit(const float* __restrict__ p,
                                               const float* __restrict__ b,
                                               float* __restrict__ z) {
  int i = blockIdx.x * 256 + threadIdx.x;
  if (i < N_NODES * H_DIM) z[i] = p[i] + b[i & 31];
}

__global__ __launch_bounds__(256) void k_scatter(
    const int* __restrict__ row, const int* __restrict__ col,
    const float* __restrict__ p, float* __restrict__ z) {
  long long t = (long long)blockIdx.x * 256 + threadIdx.x;
  int e = (int)(t >> 5);
  int c = (int)(t & 31);
  if (e < E_EDGES) {
    int s = col[e], d = row[e];
    atomicAdd(&z[(size_t)d * H_DIM + c], p[(size_t)s * H_DIM + c]);
  }
}

__global__ __launch_bounds__(256) void k_mlp_stats(
    const float* __restrict__ z, const float* __restrict__ W,
    const float* __restrict__ b, float* __restrict__ hpre,
    float* __restrict__ stats) {
  __shared__ float as_[64 * 36];
  __shared__ float ws[32 * 36];
  __shared__ float red[512];
  const int tid = threadIdx.x;
  for (int i = tid; i < 1024; i += 256) {
    int k = i >> 5, c = i & 31;
    ws[c * 36 + k] = W[(size_t)k * H_DIM + c];
  }
  const int r0 = blockIdx.x * 64;
  for (int i = tid; i < 2048; i += 256) {
    int r = i >> 5, c = i & 31;
    int gr = r0 + r;
    float v = (gr < N_NODES) ? z[(size_t)gr * H_DIM + c] : 0.f;
    as_[r * 36 + c] = fmaxf(v, 0.f);
  }
  __syncthreads();
  const int c = tid & 31, rg = tid >> 5;
  float4 wc[8];
  #pragma unroll
  for (int q = 0; q < 8; q++) wc[q] = *(float4*)&ws[c * 36 + q * 4];
  const float bc = b[c];
  float lsum = 0.f, lsq = 0.f;
  #pragma unroll
  for (int i = 0; i < 8; i++) {
    int r = rg * 8 + i;
    float a = bc;
    #pragma unroll
    for (int q = 0; q < 8; q++) {
      float4 h4 = *(float4*)&as_[r * 36 + q * 4];
      a += h4.x * wc[q].x + h4.y * wc[q].y + h4.z * wc[q].z + h4.w * wc[q].w;
    }
    int gr = r0 + r;
    if (gr < N_NODES) {
      hpre[(size_t)gr * H_DIM + c] = a;
      lsum += a; lsq += a * a;
    }
  }
  __syncthreads();
  red[tid] = lsum; red[256 + tid] = lsq;
  __syncthreads();
  if (tid < 32) {
    float s = 0.f, q = 0.f;
    #pragma unroll
    for (int g = 0; g < 8; g++) { s += red[g * 32 + tid]; q += red[256 + g * 32 + tid]; }
    atomicAdd(&stats[tid], s);
    atomicAdd(&stats[32 + tid], q);
  }
}

// ---------------------------------------------------------------------------
// K5: p = BN(hpre) @ W  (BN finalize folded in from raw stats)
// ---------------------------------------------------------------------------
__global__ __launch_bounds__(256) void k_gemm32_affine(
    const float* __restrict__ hpre, const float* __restrict__ stats,
    const float* __restrict__ g, const float* __restrict__ be,
    const float* __restrict__ W, float* __restrict__ p) {
  __shared__ float hs[64 * 36];
  __shared__ float ws[32 * 36];
  __shared__ float ssl[64];
  const int tid = threadIdx.x;
  if (tid < 32) {
    float m = stats[tid] * (1.f / N_NODES);
    float v = stats[32 + tid] * (1.f / N_NODES) - m * m;
    float sc = g[tid] * rsqrtf(v + BN_EPS);
    ssl[tid] = sc;
    ssl[32 + tid] = be[tid] - m * sc;
  }
  for (int i = tid; i < 1024; i += 256) {
    int k = i >> 5, c = i & 31;
    ws[c * 36 + k] = W[(size_t)k * H_DIM + c];
  }
  __syncthreads();
  const int r0 = blockIdx.x * 64;
  for (int i = tid; i < 2048; i += 256) {
    int r = i >> 5, c = i & 31;
    int gr = r0 + r;
    float v = (gr < N_NODES) ? hpre[(size_t)gr * H_DIM + c] * ssl[c] + ssl[32 + c] : 0.f;
    hs[r * 36 + c] = v;
  }
  __syncthreads();
  const int c = tid & 31, rg = tid >> 5;
  float4 wc[8];
  #pragma unroll
  for (int q = 0; q < 8; q++) wc[q] = *(float4*)&ws[c * 36 + q * 4];
  #pragma unroll
  for (int i = 0; i < 8; i++) {
    int r = rg * 8 + i;
    float a = 0.f;
    #pragma unroll
    for (int q = 0; q < 8; q++) {
      float4 h4 = *(float4*)&hs[r * 36 + q * 4];
      a += h4.x * wc[q].x + h4.y * wc[q].y + h4.z * wc[q].z + h4.w * wc[q].w;
    }
    int gr = r0 + r;
    if (gr < N_NODES) p[(size_t)gr * H_DIM + c] = a;
  }
}

// ---------------------------------------------------------------------------
// K6: heads: out = relu(BN(hpre)@Wf1 + bf1) @ Wf2 + bf2 (BN folded in)
// ---------------------------------------------------------------------------
__global__ __launch_bounds__(256) void k_heads(
    const float* __restrict__ hpre, const float* __restrict__ stats,
    const float* __restrict__ g, const float* __restrict__ be,
    const float* __restrict__ W1, const float* __restrict__ b1,
    const float* __restrict__ W2, const float* __restrict__ b2,
    float* __restrict__ out) {
  __shared__ float hs[64 * 36];
  __shared__ float fs[64 * 36];
  __shared__ float w1[32 * 36];
  __shared__ float w2[41 * 36];
  __shared__ float ssl[64];
  const int tid = threadIdx.x;
  if (tid < 32) {
    float m = stats[tid] * (1.f / N_NODES);
    float v = stats[32 + tid] * (1.f / N_NODES) - m * m;
    float sc = g[tid] * rsqrtf(v + BN_EPS);
    ssl[tid] = sc;
    ssl[32 + tid] = be[tid] - m * sc;
  }
  for (int i = tid; i < 1024; i += 256) {
    int k = i >> 5, c = i & 31;
    w1[c * 36 + k] = W1[(size_t)k * H_DIM + c];
  }
  for (int i = tid; i < 41 * 32; i += 256) {
    int j = i >> 5, k = i & 31;
    w2[j * 36 + k] = W2[(size_t)k * C_OUT + j];
  }
  __syncthreads();
  const int r0 = blockIdx.x * 64;
  for (int i = tid; i < 2048; i += 256) {
    int r = i >> 5, c = i & 31;
    int gr = r0 + r;
    hs[r * 36 + c] = (gr < N_NODES) ? hpre[(size_t)gr * H_DIM + c] * ssl[c] + ssl[32 + c] : 0.f;
  }
  __syncthreads();
  {
    const int c = tid & 31, rg = tid >> 5;
    float4 wc[8];
    #pragma unroll
    for (int q = 0; q < 8; q++) wc[q] = *(float4*)&w1[c * 36 + q * 4];
    const float bc = b1[c];
    #pragma unroll
    for (int i = 0; i < 8; i++) {
      int r = rg * 8 + i;
      float a = bc;
      #pragma unroll
      for (int q = 0; q < 8; q++) {
        float4 h4 = *(float4*)&hs[r * 36 + q * 4];
        a += h4.x * wc[q].x + h4.y * wc[q].y + h4.z * wc[q].z + h4.w * wc[q].w;
      }
      fs[r * 36 + c] = fmaxf(a, 0.f);
    }
  }
  __syncthreads();
  for (int idx = tid; idx < 64 * C_OUT; idx += 256) {
    int r = idx / C_OUT, j = idx - r * C_OUT;
    int gr = r0 + r;
    if (gr < N_NODES) {
      float a = b2[j];
      #pragma unroll
      for (int q = 0; q < 8; q++) {
        float4 f4 = *(float4*)&fs[r * 36 + q * 4];
        float4 w4 = *(float4*)&w2[j * 36 + q * 4];
        a += f4.x * w4.x + f4.y * w4.y + f4.z * w4.z + f4.w * w4.w;
      }
      out[(size_t)gr * C_OUT + j] = a;
    }
  }
}

// ---------------------------------------------------------------------------
extern "C" void kernel_launch(void* const* d_in, const int* in_sizes, int n_in,
                              void* d_out, int out_size, void* d_ws, size_t ws_size,
                              hipStream_t stream) {
  const float* x   = (const float*)d_in[0];
  const int* row   = (const int*)d_in[1];
  const int* col   = (const int*)d_in[2];
  const float* W1a = (const float*)d_in[3];
  const float* b1a = (const float*)d_in[4];
  const float* W1b = (const float*)d_in[5];
  const float* b1b = (const float*)d_in[6];
  const float* g1  = (const float*)d_in[7];
  const float* be1 = (const float*)d_in[8];
  const float* W2a = (const float*)d_in[9];
  const float* b2a = (const float*)d_in[10];
  const float* W2b = (const float*)d_in[11];
  const float* b2b = (const float*)d_in[12];
  const float* g2  = (const float*)d_in[13];
  const float* be2 = (const float*)d_in[14];
  const float* Wf1 = (const float*)d_in[15];
  const float* bf1 = (const float*)d_in[16];
  const float* Wf2 = (const float*)d_in[17];
  const float* bf2 = (const float*)d_in[18];
  float* out = (float*)d_out;

  float* ws = (float*)d_ws;
  const size_t NH = (size_t)N_NODES * H_DIM;        // 1.6M
  float* pA    = ws;
  float* zB    = ws + NH;                           // fallback only
  float* hC    = ws + 2 * NH;
  float* stats = ws + 3 * NH;                       // 128 floats
  int*   startA = (int*)(ws + 3 * NH + 256);        // N+1 (pad 50016)
  int*   cursor = startA + 50016;                   // N
  int*   deg    = cursor + 50016;                   // N
  int*   ecol   = deg + 50016;                      // E
  int*   bsum   = ecol + E_EDGES;                   // 256
  int*   boff   = bsum + 256;                       // 256
  const size_t need_bytes = ((3 * NH + 256) + 3 * 50016 + E_EDGES + 512) * 4;
  const bool use_csr = (ws_size >= need_bytes);

  hipMemsetAsync(stats, 0, 128 * sizeof(float), stream);

  const int g64   = (N_NODES + 63) / 64;            // 782
  const int gE    = (E_EDGES + 255) / 256;          // 3125
  const int gN    = (N_NODES + 255) / 256;          // 196
  const int gScat = (E_EDGES * 32 + 255) / 256;     // 100000

  if (use_csr) {
    hipMemsetAsync(deg, 0, 50000 * sizeof(int), stream);
    k_hist <<<gE, 256, 0, stream>>>(row, deg);
    k_scanA<<<gN, 256, 0, stream>>>(deg, startA, bsum);
    k_scanB<<<1, 256, 0, stream>>>(bsum, boff, gN);
    k_scanC<<<gN, 256, 0, stream>>>(startA, boff, cursor);
    k_fill <<<gE, 256, 0, stream>>>(row, col, cursor, ecol);
  }

  // conv1 big GEMM (MFMA split-bf16)
  k_gemm_mfma<<<g64, 256, 0, stream>>>(x, W1a, pA);
  if (use_csr) {
    k_gather_mlp<<<g64, 256, 0, stream>>>(pA, b1a, startA, ecol, W1b, b1b, hC, stats);
  } else {
    k_zinit<<<g64 * 8, 256, 0, stream>>>(pA, b1a, zB);
    k_scatter<<<gScat, 256, 0, stream>>>(row, col, pA, zB);
    k_mlp_stats<<<g64, 256, 0, stream>>>(zB, W1b, b1b, hC, stats);
  }
  // conv2 (BN1 folded into GEMM)
  k_gemm32_affine<<<g64, 256, 0, stream>>>(hC, stats, g1, be1, W2a, pA);
  if (use_csr) {
    k_gather_mlp<<<g64, 256, 0, stream>>>(pA, b2a, startA, ecol, W2b, b2b, hC, stats + 64);
  } else {
    k_zinit<<<g64 * 8, 256, 0, stream>>>(pA, b2a, zB);
    k_scatter<<<gScat, 256, 0, stream>>>(row, col, pA, zB);
    k_mlp_stats<<<g64, 256, 0, stream>>>(zB, W2b, b2b, hC, stats + 64);
  }
  // heads (BN2 folded in)
  k_heads<<<g64, 256, 0, stream>>>(hC, stats + 64, g2, be2, Wf1, bf1, Wf2, bf2, out);
}